// Round 1
// baseline (442.391 us; speedup 1.0000x reference)
//
#include <hip/hip_runtime.h>

#define B_ 8
#define C_ 64
#define H_ 256
#define W_ 256
#define WT 16      // w-tile per block
#define ST 64      // h-strip per block
#define NT 1024    // threads per block (64 c x 16 w)
#define LROW 24    // LDS row stride in dwords (20 cols + 4 pad -> 2-way banks = free)

__global__ __launch_bounds__(NT) void kpn5x5_kernel(const float* __restrict__ x,
                                                    const float* __restrict__ wgt,
                                                    float* __restrict__ out) {
  const int tid = threadIdx.x;
  const int c = tid >> 4;          // 0..63
  const int w = tid & 15;          // 0..15
  const int w0 = blockIdx.x * WT;
  const int h0 = blockIdx.y * ST;
  const int b  = blockIdx.z;
  const int wg = w0 + w;

  __shared__ float pl[2][C_ * LROW];   // 2-slot ring of one x-row (all 64 c, 20 cols)

  // cooperative staging: 64 c * 20 cols = 1280 elements, <=2 per thread
  const int idx0 = tid;                      // always < 1280
  const int cc0 = idx0 / 20, j0 = idx0 - cc0 * 20;
  const int idx1 = tid + NT;
  const int cc1 = idx1 / 20, j1 = idx1 - cc1 * 20;
  const bool has1 = (idx1 < C_ * 20);
  const int col0 = w0 - 2 + j0;
  const int col1 = w0 - 2 + j1;
  const float* xb = x + (b * C_) * (H_ * W_);

  auto fetch = [&](int row, int cc, int col) -> float {
    if (row < 0 || row >= H_ || col < 0 || col < 0 + 0 ? false : col >= W_) return 0.0f;
    return xb[(cc * H_ + row) * W_ + col];
  };

  float win[5][5];

  // ---- prime: rows h0-2 .. h0+1 into the register window ----
  for (int i = 0; i < 4; ++i) {
    int r = h0 - 2 + i;
    int s = r & 1;
    pl[s][cc0 * LROW + j0] = (r >= 0 && r < H_ && col0 >= 0 && col0 < W_)
                               ? xb[(cc0 * H_ + r) * W_ + col0] : 0.0f;
    if (has1)
      pl[s][cc1 * LROW + j1] = (r >= 0 && r < H_ && col1 >= 0 && col1 < W_)
                                 ? xb[(cc1 * H_ + r) * W_ + col1] : 0.0f;
    __syncthreads();
#pragma unroll
    for (int d = 0; d < 5; ++d) win[i][d] = pl[s][c * LROW + w + d];
    __syncthreads();
  }
  // stage row h0+2 for the first step (slot h0&1)
  {
    int r = h0 + 2;
    int s = r & 1;
    pl[s][cc0 * LROW + j0] = (r < H_ && col0 >= 0 && col0 < W_)
                               ? xb[(cc0 * H_ + r) * W_ + col0] : 0.0f;
    if (has1)
      pl[s][cc1 * LROW + j1] = (r < H_ && col1 >= 0 && col1 < W_)
                                 ? xb[(cc1 * H_ + r) * W_ + col1] : 0.0f;
    __syncthreads();
  }

  // prime weights for row h0 (per-pixel, shared by all 64 channels of this block)
  float wc[25];
  {
    const int wb = (b * H_ + h0) * W_ + wg;
#pragma unroll
    for (int k = 0; k < 25; ++k) wc[k] = wgt[wb + k * (B_ * H_ * W_)];
  }

  float* outp = out + ((b * C_ + c) * H_) * W_ + wg;

  for (int h = h0; h < h0 + ST; ++h) {
    // --- prefetch x row h+3 into regs (latency hidden behind this step's compute)
    const int rn = h + 3;
    float s0 = (rn < H_ && col0 >= 0 && col0 < W_) ? xb[(cc0 * H_ + rn) * W_ + col0] : 0.0f;
    float s1 = 0.0f;
    if (has1 && rn < H_ && col1 >= 0 && col1 < W_) s1 = xb[(cc1 * H_ + rn) * W_ + col1];

    // --- prefetch weights for row h+1 (clamped at strip/image end; values unused past end)
    float wn[25];
    {
      const int hn = (h + 1 < H_) ? h + 1 : H_ - 1;
      const int wb = (b * H_ + hn) * W_ + wg;
#pragma unroll
      for (int k = 0; k < 25; ++k) wn[k] = wgt[wb + k * (B_ * H_ * W_)];
    }

    // --- bottom window row = row h+2 from LDS slot h&1 (5 taps, bank-conflict-free)
    {
      const float* p = &pl[h & 1][c * LROW + w];
#pragma unroll
      for (int d = 0; d < 5; ++d) win[4][d] = p[d];
    }

    // --- 25 FMAs
    float acc = 0.0f;
#pragma unroll
    for (int i = 0; i < 5; ++i)
#pragma unroll
      for (int d = 0; d < 5; ++d) acc += win[i][d] * wc[i * 5 + d];

    outp[h * W_] = acc;   // 16 consecutive lanes -> full 64B lines

    // --- shift window up by one row
#pragma unroll
    for (int i = 0; i < 4; ++i)
#pragma unroll
      for (int d = 0; d < 5; ++d) win[i][d] = win[i + 1][d];

    // --- roll weights
#pragma unroll
    for (int k = 0; k < 25; ++k) wc[k] = wn[k];

    // --- commit prefetched x row h+3 to slot (h+1)&1
    {
      const int s = (h + 1) & 1;
      pl[s][cc0 * LROW + j0] = s0;
      if (has1) pl[s][cc1 * LROW + j1] = s1;
    }
    __syncthreads();
  }
}

extern "C" void kernel_launch(void* const* d_in, const int* in_sizes, int n_in,
                              void* d_out, int out_size, void* d_ws, size_t ws_size,
                              hipStream_t stream) {
  const float* x = (const float*)d_in[0];
  const float* wgt = (const float*)d_in[1];
  float* out = (float*)d_out;
  dim3 grid(W_ / WT, H_ / ST, B_);   // 16 x 4 x 8 = 512 blocks
  dim3 block(NT);
  kpn5x5_kernel<<<grid, block, 0, stream>>>(x, wgt, out);
}

// Round 3
// 327.902 us; speedup vs baseline: 1.3492x; 1.3492x over previous
//
#include <hip/hip_runtime.h>

#define B_ 8
#define C_ 64
#define H_ 256
#define W_ 256
#define ST 32                 // h-rows per block strip
#define NCH 4                 // channels per thread
#define WSTR (B_ * H_ * W_)   // weight tap stride in elements

// 256 threads = 4 waves. Wave = 64 consecutive w; thread owns 4 channels.
// NO LDS anywhere: horizontal taps are direct global loads (L1 absorbs the
// 5x overlap), vertical reuse lives in a 5-row register window rotated by
// compile-time modular indices (10-step unroll; 10 == 0 mod 5).
__global__ __launch_bounds__(256) void kpn5x5_v3(const float* __restrict__ x,
                                                 const float* __restrict__ wgt,
                                                 float* __restrict__ out) {
  const int tid  = threadIdx.x;
  const int lane = tid & 63;
  const int wv   = tid >> 6;               // 0..3
  const int w0   = blockIdx.x * 64;
  const int h0   = blockIdx.y * ST;
  const int bz   = blockIdx.z;             // = cgrp*8 + b  (cgrp slowest ->
  const int b    = bz & 7;                 //   same-XCD weight sharing)
  const int c0   = (bz >> 3) * 16 + wv * NCH;

  // h-invariant per-thread column offsets (clamped) + 0/1 masks
  int   voff[5];
  float msk[5];
#pragma unroll
  for (int d = 0; d < 5; ++d) {
    const int col = w0 + lane - 2 + d;
    const bool ok = (col >= 0) && (col < W_);
    voff[d] = ok ? col : 0;
    msk[d]  = ok ? 1.0f : 0.0f;
  }

  const float* xc = x + (size_t)(b * C_ + c0) * (H_ * W_);   // wave-uniform
  float win[NCH][5][5];
  float wc[25];

  // ---- prologue: window rows 0..3 = x rows h0-2 .. h0+1 ----
#pragma unroll
  for (int i = 0; i < 4; ++i) {
    const int r = h0 - 2 + i;
    if ((unsigned)r < (unsigned)H_) {          // wave-uniform branch
#pragma unroll
      for (int ch = 0; ch < NCH; ++ch) {
        const float* p = xc + (size_t)ch * (H_ * W_) + (size_t)r * W_;
#pragma unroll
        for (int d = 0; d < 5; ++d) win[ch][i][d] = p[voff[d]] * msk[d];
      }
    } else {
#pragma unroll
      for (int ch = 0; ch < NCH; ++ch)
#pragma unroll
        for (int d = 0; d < 5; ++d) win[ch][i][d] = 0.0f;
    }
  }

  // weights for row h0: uniform base + lane -> SGPR base, one voffset
  {
    const float* wq = wgt + ((size_t)b * H_ + h0) * W_ + w0;  // uniform
#pragma unroll
    for (int k = 0; k < 25; ++k) wc[k] = wq[(size_t)k * WSTR + lane];
  }

  // step U (compile-time 0..9): load x row h+2 into win[(U+4)%5], FMA rows
  // (U+i)%5 against wc (weights row h), store, reload wc <- row h+1.
#define STEP(U) do {                                                        \
    const int h_  = hb + (U);                                               \
    const int rb_ = h_ + 2;                                                 \
    if (rb_ < H_) {                                                         \
      _Pragma("unroll")                                                     \
      for (int ch = 0; ch < NCH; ++ch) {                                    \
        const float* p_ = xc + (size_t)ch * (H_ * W_) + (size_t)rb_ * W_;   \
        _Pragma("unroll")                                                   \
        for (int d = 0; d < 5; ++d)                                         \
          win[ch][((U) + 4) % 5][d] = p_[voff[d]] * msk[d];                 \
      }                                                                     \
    } else {                                                                \
      _Pragma("unroll")                                                     \
      for (int ch = 0; ch < NCH; ++ch)                                      \
        _Pragma("unroll")                                                   \
        for (int d = 0; d < 5; ++d) win[ch][((U) + 4) % 5][d] = 0.0f;       \
    }                                                                       \
    float a_[NCH];                                                          \
    _Pragma("unroll")                                                       \
    for (int ch = 0; ch < NCH; ++ch) a_[ch] = 0.0f;                         \
    _Pragma("unroll")                                                       \
    for (int i = 0; i < 5; ++i)                                             \
      _Pragma("unroll")                                                     \
      for (int d = 0; d < 5; ++d) {                                         \
        const float wt_ = wc[i * 5 + d];                                    \
        _Pragma("unroll")                                                   \
        for (int ch = 0; ch < NCH; ++ch)                                    \
          a_[ch] += win[ch][((U) + i) % 5][d] * wt_;                        \
      }                                                                     \
    {                                                                       \
      const size_t ob_ = ((size_t)(b * C_ + c0) * H_ + (h0 + sb + (U)))     \
                           * W_ + w0 + lane;                                \
      _Pragma("unroll")                                                     \
      for (int ch = 0; ch < NCH; ++ch)                                      \
        out[ob_ + (size_t)ch * (H_ * W_)] = a_[ch];                         \
    }                                                                       \
    {                                                                       \
      int hw_ = h_ + 1; if (hw_ > H_ - 1) hw_ = H_ - 1;                     \
      const float* wq_ = wgt + ((size_t)b * H_ + hw_) * W_ + w0;            \
      _Pragma("unroll")                                                     \
      for (int k = 0; k < 25; ++k) wc[k] = wq_[(size_t)k * WSTR + lane];    \
    }                                                                       \
  } while (0)

  int hb = h0, sb = 0;
  for (int g = 0; g < 3; ++g) {            // 3*10 + 2 = 32 rows
    STEP(0); STEP(1); STEP(2); STEP(3); STEP(4);
    STEP(5); STEP(6); STEP(7); STEP(8); STEP(9);
    hb += 10; sb += 10;
  }
  STEP(0); STEP(1);
#undef STEP
}

extern "C" void kernel_launch(void* const* d_in, const int* in_sizes, int n_in,
                              void* d_out, int out_size, void* d_ws, size_t ws_size,
                              hipStream_t stream) {
  const float* x   = (const float*)d_in[0];
  const float* wgt = (const float*)d_in[1];
  float* out = (float*)d_out;
  dim3 grid(W_ / 64, H_ / ST, (C_ / (NCH * 4)) * B_);  // 4 x 8 x 32 = 1024 blocks
  dim3 block(256);
  kpn5x5_v3<<<grid, block, 0, stream>>>(x, wgt, out);
}